// Round 9
// baseline (5839.235 us; speedup 1.0000x reference)
//
#include <hip/hip_runtime.h>
#include <math.h>

#define S_LEN 256
#define BATCH 64
#define EDIM  256
#define HDIM  512

typedef float f32x4  __attribute__((ext_vector_type(4)));
typedef float f32x16 __attribute__((ext_vector_type(16)));

// ---- cache-bypassing (coherence-point) 16B load/store: sc0 sc1 ----
__device__ __forceinline__ void ld_b128_sc(f32x4* v, const float* p) {
  asm volatile("global_load_dwordx4 %0, %1, off sc0 sc1"
               : "=v"(*v) : "v"(p) : "memory");
}
__device__ __forceinline__ void st_b128_sc(float* p, f32x4 v) {
  asm volatile("global_store_dwordx4 %0, %1, off sc0 sc1"
               :: "v"(p), "v"(v) : "memory");
}

// ---------------- Phase A: gi = emb[sent] @ Wih^T + bih ----------------
// R6-proven: 512 thr/block, 128x128 tile, 8Mx4N micro, per-kc A+B staging
// (33 KB LDS -> 4 blocks/CU). grid (32, 12, 2) = 64 slots per dispatch.
__global__ __launch_bounds__(512) void gi_gemm(
    const int* __restrict__ sent, const float* __restrict__ emb,
    const float* __restrict__ Wih_f, const float* __restrict__ bih_f,
    const float* __restrict__ Wih_b, const float* __restrict__ bih_b,
    float* __restrict__ gi, int abs_base, int buf_base, int dstride)
{
  const int d  = blockIdx.z;
  const int bx = blockIdx.x;
  const int by = blockIdx.y;
  const float* W    = d ? Wih_b : Wih_f;
  const float* bias = d ? bih_b : bih_f;

  __shared__ int    tok[128];
  __shared__ float4 As4[128][8];
  __shared__ float4 Bs4[128][8];

  const int tid = threadIdx.x;
  if (tid < 128) {
    int s_lc = 2 * bx + (tid >> 6);
    int slot = abs_base + s_lc;
    int srow = (d == 0) ? slot : (S_LEN - 1 - slot);
    tok[tid] = sent[srow * BATCH + (tid & 63)];
  }

  float acc[8][4];
#pragma unroll
  for (int i = 0; i < 8; ++i)
#pragma unroll
    for (int j = 0; j < 4; ++j) acc[i][j] = 0.f;

  const int tb = tid & 15;   // M group
  const int tn = tid >> 4;   // 0..31: N group of 4

  for (int kc = 0; kc < 8; ++kc) {
    __syncthreads();
#pragma unroll
    for (int it = 0; it < 2; ++it) {
      int flat = tid + 512 * it;        // 0..1023
      int row  = flat >> 3;
      int k4   = flat & 7;
      int sw   = k4 ^ (row & 7) ^ ((row >> 3) & 7);
      As4[row][sw] = *(const float4*)&emb[(size_t)tok[row] * EDIM + kc * 32 + 4 * k4];
      Bs4[row][sw] = *(const float4*)&W[(size_t)(by * 128 + row) * EDIM + kc * 32 + 4 * k4];
    }
    __syncthreads();
#pragma unroll
    for (int k4 = 0; k4 < 8; ++k4) {
      float4 a[8];
#pragma unroll
      for (int i = 0; i < 8; ++i)
        a[i] = As4[8 * tb + i][k4 ^ i ^ (tb & 7)];
#pragma unroll
      for (int j = 0; j < 4; ++j) {
        int r = 4 * tn + j;
        float4 bf = Bs4[r][k4 ^ (r & 7) ^ ((r >> 3) & 7)];
#pragma unroll
        for (int i = 0; i < 8; ++i)
          acc[i][j] += a[i].x * bf.x + a[i].y * bf.y
                     + a[i].z * bf.z + a[i].w * bf.w;
      }
    }
  }

  const int s_lc = 2 * bx + (tb >> 3);
  const int brow = 8 * (tb & 7);
#pragma unroll
  for (int j = 0; j < 4; ++j) {
    int n = by * 128 + 4 * tn + j;
    float bs = bias[n];
    int g = n >> 9, u = n & 511;
    size_t base = ((((size_t)d * dstride + buf_base + s_lc) * 3 + g) * HDIM + u) * BATCH + brow;
    float4 v0 = { acc[0][j] + bs, acc[1][j] + bs, acc[2][j] + bs, acc[3][j] + bs };
    float4 v1 = { acc[4][j] + bs, acc[5][j] + bs, acc[6][j] + bs, acc[7][j] + bs };
    *(float4*)&gi[base]     = v0;
    *(float4*)&gi[base + 4] = v1;
  }
}

// ---------------- Phase B: barriered recurrent scan (v7) ----------------
// 256 WGs x 256 thr. WG = (dir, 4 hidden units); 1 unit per wave.
// v7: weights fetched via s_load_dwordx16 into SGPRs (scalar pipe) --
// eliminates the 384 wave-uniform LDS broadcast reads per wave per step
// (75% of LDS traffic). FMA chain shape identical -> bitwise-same h.
// h via sc0sc1 global exchange; split-half staging overlap; epoch barrier.
__global__ __launch_bounds__(256, 1) void scan_kernel(
    const float* __restrict__ gi, float* __restrict__ hs,
    const float* __restrict__ Whh_f, const float* __restrict__ bhh_f,
    const float* __restrict__ Whh_b, const float* __restrict__ bhh_b,
    unsigned* cnt, int step0, int nsteps)
{
  const int w   = blockIdx.x;
  const int d   = w >> 7;
  const int ub  = w & 127;
  const int tid = threadIdx.x;
  const int tx  = tid & 63;
  const int ty  = __builtin_amdgcn_readfirstlane(tid >> 6);   // 0..3 wave-uniform
  const int u   = 4 * ub + ty;                                 // this wave's unit

  const float* Whh = d ? Whh_b : Whh_f;
  const float* bhh = d ? bhh_b : bhh_f;

  __shared__ float hl2[2][64][260];   // h(t-1) halves: [half][batch][k-local]
  __shared__ float hb[64][4];

  const float br = bhh[u];
  const float bz = bhh[512 + u];
  const float bn = bhh[1024 + u];
  // wave-uniform weight-row base pointers (SGPR pairs for s_load)
  const int us = __builtin_amdgcn_readfirstlane(u);
  const float* wRp = Whh + (size_t)(us          ) * HDIM;
  const float* wZp = Whh + (size_t)(512  + us   ) * HDIM;
  const float* wNp = Whh + (size_t)(1024 + us   ) * HDIM;
  const int uhalf = u >> 8, ulo = u & 255;

  // prefetch gi for step 0
  float ir, iz, in_;
  {
    const float* gb = gi + ((size_t)d * nsteps) * 3 * HDIM * BATCH;
    ir  = gb[((size_t)0 * HDIM + u) * BATCH + tx];
    iz  = gb[((size_t)1 * HDIM + u) * BATCH + tx];
    in_ = gb[((size_t)2 * HDIM + u) * BATCH + tx];
  }

  for (int l = 0; l < nsteps; ++l) {
    const int gs      = step0 + l;
    const int t_store = (d == 0) ? gs : (S_LEN - 1 - gs);
    const int t_prev  = (d == 0) ? (gs - 1) : (S_LEN - gs);

    float aR = 0.f, aZ = 0.f, aN = 0.f, hp = 0.f;

    if (gs > 0) {
      const float* hpg = hs + ((size_t)d * S_LEN + t_prev) * HDIM * BATCH;
      f32x4 buf[32];
      // issue all 32 loads: j<16 -> k half 0, j>=16 -> k half 1
#pragma unroll
      for (int j = 0; j < 32; ++j) {
        int half = j >> 4;
        int flat = tid + 256 * (j & 15);          // 0..4095 float4s per half
        ld_b128_sc(&buf[j], &hpg[(size_t)(flat >> 6) * HDIM + half * 256 + 4 * (flat & 63)]);
      }
      asm volatile("s_waitcnt vmcnt(16)" ::: "memory");   // half 0 arrived
      __builtin_amdgcn_sched_barrier(0);
#pragma unroll
      for (int j = 0; j < 16; ++j) {
        int flat = tid + 256 * j;
        *(f32x4*)&hl2[0][flat >> 6][4 * (flat & 63)] = buf[j];
      }
      __syncthreads();

      if (uhalf == 0) hp = hl2[0][tx][ulo];
      {
        const float* hrow = &hl2[0][tx][0];
#pragma unroll 4
        for (int c = 0; c < 16; ++c) {            // k in [0,256)
          f32x16 wr, wz, wn;
          asm volatile(
            "s_load_dwordx16 %0, %3, 0x0\n\t"
            "s_load_dwordx16 %1, %4, 0x0\n\t"
            "s_load_dwordx16 %2, %5, 0x0\n\t"
            "s_waitcnt lgkmcnt(0)"
            : "=&s"(wr), "=&s"(wz), "=&s"(wn)
            : "s"(wRp + 16 * c), "s"(wZp + 16 * c), "s"(wNp + 16 * c));
#pragma unroll
          for (int q = 0; q < 4; ++q) {
            f32x4 h4 = *(const f32x4*)&hrow[16 * c + 4 * q];
            aR += h4.x * wr[4*q] + h4.y * wr[4*q+1] + h4.z * wr[4*q+2] + h4.w * wr[4*q+3];
            aZ += h4.x * wz[4*q] + h4.y * wz[4*q+1] + h4.z * wz[4*q+2] + h4.w * wz[4*q+3];
            aN += h4.x * wn[4*q] + h4.y * wn[4*q+1] + h4.z * wn[4*q+2] + h4.w * wn[4*q+3];
          }
        }
      }

      asm volatile("s_waitcnt vmcnt(0)" ::: "memory");    // half 1 arrived
      __builtin_amdgcn_sched_barrier(0);
#pragma unroll
      for (int j = 16; j < 32; ++j) {
        int flat = tid + 256 * (j & 15);
        *(f32x4*)&hl2[1][flat >> 6][4 * (flat & 63)] = buf[j];
      }
      __syncthreads();

      if (uhalf == 1) hp = hl2[1][tx][ulo];
      {
        const float* hrow = &hl2[1][tx][0];
        const float* wRh = wRp + 256;
        const float* wZh = wZp + 256;
        const float* wNh = wNp + 256;
#pragma unroll 4
        for (int c = 0; c < 16; ++c) {            // k in [256,512)
          f32x16 wr, wz, wn;
          asm volatile(
            "s_load_dwordx16 %0, %3, 0x0\n\t"
            "s_load_dwordx16 %1, %4, 0x0\n\t"
            "s_load_dwordx16 %2, %5, 0x0\n\t"
            "s_waitcnt lgkmcnt(0)"
            : "=&s"(wr), "=&s"(wz), "=&s"(wn)
            : "s"(wRh + 16 * c), "s"(wZh + 16 * c), "s"(wNh + 16 * c));
#pragma unroll
          for (int q = 0; q < 4; ++q) {
            f32x4 h4 = *(const f32x4*)&hrow[16 * c + 4 * q];
            aR += h4.x * wr[4*q] + h4.y * wr[4*q+1] + h4.z * wr[4*q+2] + h4.w * wr[4*q+3];
            aZ += h4.x * wz[4*q] + h4.y * wz[4*q+1] + h4.z * wz[4*q+2] + h4.w * wz[4*q+3];
            aN += h4.x * wn[4*q] + h4.y * wn[4*q+1] + h4.z * wn[4*q+2] + h4.w * wn[4*q+3];
          }
        }
      }
    }

    float r  = 1.f / (1.f + expf(-(ir + aR + br)));
    float zg = 1.f / (1.f + expf(-(iz + aZ + bz)));
    float n  = tanhf(in_ + r * (aN + bn));
    float hn = (1.f - zg) * n + zg * hp;

    __syncthreads();
    hb[tx][ty] = hn;
    __syncthreads();
    if (tid < 64) {
      f32x4 v = *(const f32x4*)&hb[tid][0];
      st_b128_sc(&hs[(((size_t)d * S_LEN + t_store) * BATCH + tid) * HDIM + 4 * ub], v);
      asm volatile("s_waitcnt vmcnt(0)" ::: "memory");    // wave0: all 64 stores at L3
    }
    // arrive (tid0 is in wave 0 -> ordered after the vmcnt above)
    if (tid == 0)
      __hip_atomic_fetch_add(&cnt[(w & 31) << 4], 1u,
                             __ATOMIC_RELAXED, __HIP_MEMORY_SCOPE_AGENT);
    // prefetch gi(l+1) while waiting
    if (l + 1 < nsteps) {
      const float* gb = gi + ((size_t)d * nsteps + l + 1) * 3 * HDIM * BATCH;
      ir  = gb[((size_t)0 * HDIM + u) * BATCH + tx];
      iz  = gb[((size_t)1 * HDIM + u) * BATCH + tx];
      in_ = gb[((size_t)2 * HDIM + u) * BATCH + tx];
    }
    if (w == 0) {
      if (tid < 32) {                    // all in wave 0: polls precede publish
        unsigned tgt = 8u * (unsigned)(gs + 1);
        while (__hip_atomic_load(&cnt[tid << 4],
                                 __ATOMIC_RELAXED, __HIP_MEMORY_SCOPE_AGENT) < tgt)
          __builtin_amdgcn_s_sleep(1);
      }
      if (tid == 0)
        __hip_atomic_store(&cnt[32 << 4], (unsigned)(gs + 1),
                           __ATOMIC_RELAXED, __HIP_MEMORY_SCOPE_AGENT);
    } else {
      if (tid == 0) {
        while (__hip_atomic_load(&cnt[32 << 4],
                                 __ATOMIC_RELAXED, __HIP_MEMORY_SCOPE_AGENT)
               < (unsigned)(gs + 1))
          __builtin_amdgcn_s_sleep(1);
      }
    }
    __syncthreads();
  }
}

// ---------------- Phase C: pz / z ----------------
__global__ __launch_bounds__(256) void pz_kernel(
    const float* __restrict__ hs, const float* __restrict__ zW,
    const float* __restrict__ zb_, const float* __restrict__ noise,
    float* __restrict__ out)
{
  const int gtid = blockIdx.x * 256 + threadIdx.x;
  const int wave = gtid >> 6;
  const int lane = threadIdx.x & 63;
  const float zb = zb_[0];
  float4 w1 = *(const float4*)&zW[lane * 8];
  float4 w2 = *(const float4*)&zW[lane * 8 + 4];
  float4 w3 = *(const float4*)&zW[512 + lane * 8];
  float4 w4 = *(const float4*)&zW[512 + lane * 8 + 4];
  for (int r = wave; r < S_LEN * BATCH; r += 1024) {
    const float* hf  = hs + (size_t)r * HDIM;
    const float* hbk = hs + (size_t)(S_LEN * BATCH + r) * HDIM;
    float4 a1 = *(const float4*)&hf[lane * 8];
    float4 a2 = *(const float4*)&hf[lane * 8 + 4];
    float4 b1 = *(const float4*)&hbk[lane * 8];
    float4 b2 = *(const float4*)&hbk[lane * 8 + 4];
    float acc = a1.x * w1.x + a1.y * w1.y + a1.z * w1.z + a1.w * w1.w
              + a2.x * w2.x + a2.y * w2.y + a2.z * w2.z + a2.w * w2.w
              + b1.x * w3.x + b1.y * w3.y + b1.z * w3.z + b1.w * w3.w
              + b2.x * w4.x + b2.y * w4.y + b2.z * w4.z + b2.w * w4.w;
#pragma unroll
    for (int off = 32; off > 0; off >>= 1) acc += __shfl_down(acc, off, 64);
    if (lane == 0) {
      float p = 1.f / (1.f + expf(-(acc + zb)));
      out[r] = p;
      out[S_LEN * BATCH + r] = (noise[r] < p) ? 1.f : 0.f;
    }
  }
}

// ---------------- Phase D: per-column stable compaction ----------------
__global__ __launch_bounds__(256) void rat_kernel(
    const int* __restrict__ sent, float* __restrict__ out)
{
  const int b = blockIdx.x;
  const int s = threadIdx.x;
  __shared__ int ps[256];
  const int z = (out[S_LEN * BATCH + s * BATCH + b] > 0.5f) ? 1 : 0;
  ps[s] = z;
  __syncthreads();
#pragma unroll
  for (int off = 1; off < 256; off <<= 1) {
    int v = (s >= off) ? ps[s - off] : 0;
    __syncthreads();
    ps[s] += v;
    __syncthreads();
  }
  const int incl  = ps[s];
  const int total = ps[255];
  const int pos   = incl - z;
  if (z) out[2 * S_LEN * BATCH + pos * BATCH + b] = (float)sent[s * BATCH + b];
  if (s >= total) out[2 * S_LEN * BATCH + s * BATCH + b] = 0.f;
  if (s == 0) out[3 * S_LEN * BATCH + b] = (float)total;
}

extern "C" void kernel_launch(void* const* d_in, const int* in_sizes, int n_in,
                              void* d_out, int out_size, void* d_ws, size_t ws_size,
                              hipStream_t stream)
{
  const int*   sent  = (const int*)  d_in[0];
  const float* noise = (const float*)d_in[1];
  const float* emb   = (const float*)d_in[2];
  const float* Wih_f = (const float*)d_in[3];
  const float* Whh_f = (const float*)d_in[4];
  const float* bih_f = (const float*)d_in[5];
  const float* bhh_f = (const float*)d_in[6];
  const float* Wih_b = (const float*)d_in[7];
  const float* Whh_b = (const float*)d_in[8];
  const float* bih_b = (const float*)d_in[9];
  const float* bhh_b = (const float*)d_in[10];
  const float* zW    = (const float*)d_in[11];
  const float* zb    = (const float*)d_in[12];
  float* out = (float*)d_out;

  float* base = (float*)d_ws;
  unsigned* cnt = (unsigned*)base;                         // 4 KB reserved
  float* hs = base + 1024;                                 // 67.1 MB
  float* gi = hs + (size_t)2 * S_LEN * HDIM * BATCH;       // rest

  const size_t HS_BYTES = (size_t)2 * S_LEN * HDIM * BATCH * 4;
  const size_t PER_SLOT = (size_t)2 * 3 * HDIM * BATCH * 4;    // 786432 B
  size_t avail = (ws_size > 4096 + HS_BYTES) ? ws_size - 4096 - HS_BYTES : 0;
  int nslots = 64;
  if (avail >= 256 * PER_SLOT)      nslots = 256;
  else if (avail >= 128 * PER_SLOT) nslots = 128;
  const int nchunk = S_LEN / nslots;

  (void)hipMemsetAsync(cnt, 0, 4096, stream);
  for (int c = 0; c < nchunk; ++c) {
    for (int k = 0; k < nslots / 64; ++k)
      gi_gemm<<<dim3(32, 12, 2), 512, 0, stream>>>(
          sent, emb, Wih_f, bih_f, Wih_b, bih_b, gi,
          c * nslots + 64 * k, 64 * k, nslots);
    scan_kernel<<<dim3(256), 256, 0, stream>>>(
        gi, hs, Whh_f, bhh_f, Whh_b, bhh_b, cnt, c * nslots, nslots);
  }
  pz_kernel<<<dim3(256), 256, 0, stream>>>(hs, zW, zb, noise, out);
  rat_kernel<<<dim3(BATCH), 256, 0, stream>>>(sent, out);
}

// Round 10
// 5766.052 us; speedup vs baseline: 1.0127x; 1.0127x over previous
//
#include <hip/hip_runtime.h>
#include <math.h>

#define S_LEN 256
#define BATCH 64
#define EDIM  256
#define HDIM  512

typedef float f32x4 __attribute__((ext_vector_type(4)));

// ---- cache-bypassing (coherence-point) 16B load/store: sc0 sc1 ----
__device__ __forceinline__ void ld_b128_sc(f32x4* v, const float* p) {
  asm volatile("global_load_dwordx4 %0, %1, off sc0 sc1"
               : "=v"(*v) : "v"(p) : "memory");
}
__device__ __forceinline__ void st_b128_sc(float* p, f32x4 v) {
  asm volatile("global_store_dwordx4 %0, %1, off sc0 sc1"
               :: "v"(p), "v"(v) : "memory");
}
// wave-uniform broadcast from lane `l` (dynamic uniform -> SGPR index)
__device__ __forceinline__ float rdl(float v, int l) {
  union { float f; int i; } u;
  u.f = v;
  u.i = __builtin_amdgcn_readlane(u.i, l);
  return u.f;
}

// ---------------- Phase A: gi = emb[sent] @ Wih^T + bih ----------------
// R6/R8-proven: 512 thr/block, 128x128 tile, 8Mx4N micro, per-kc A+B staging
// (33 KB LDS -> 4 blocks/CU). grid (32, 12, 2) = 64 slots per dispatch.
__global__ __launch_bounds__(512) void gi_gemm(
    const int* __restrict__ sent, const float* __restrict__ emb,
    const float* __restrict__ Wih_f, const float* __restrict__ bih_f,
    const float* __restrict__ Wih_b, const float* __restrict__ bih_b,
    float* __restrict__ gi, int abs_base, int buf_base, int dstride)
{
  const int d  = blockIdx.z;
  const int bx = blockIdx.x;
  const int by = blockIdx.y;
  const float* W    = d ? Wih_b : Wih_f;
  const float* bias = d ? bih_b : bih_f;

  __shared__ int    tok[128];
  __shared__ float4 As4[128][8];
  __shared__ float4 Bs4[128][8];

  const int tid = threadIdx.x;
  if (tid < 128) {
    int s_lc = 2 * bx + (tid >> 6);
    int slot = abs_base + s_lc;
    int srow = (d == 0) ? slot : (S_LEN - 1 - slot);
    tok[tid] = sent[srow * BATCH + (tid & 63)];
  }

  float acc[8][4];
#pragma unroll
  for (int i = 0; i < 8; ++i)
#pragma unroll
    for (int j = 0; j < 4; ++j) acc[i][j] = 0.f;

  const int tb = tid & 15;   // M group
  const int tn = tid >> 4;   // 0..31: N group of 4

  for (int kc = 0; kc < 8; ++kc) {
    __syncthreads();
#pragma unroll
    for (int it = 0; it < 2; ++it) {
      int flat = tid + 512 * it;        // 0..1023
      int row  = flat >> 3;
      int k4   = flat & 7;
      int sw   = k4 ^ (row & 7) ^ ((row >> 3) & 7);
      As4[row][sw] = *(const float4*)&emb[(size_t)tok[row] * EDIM + kc * 32 + 4 * k4];
      Bs4[row][sw] = *(const float4*)&W[(size_t)(by * 128 + row) * EDIM + kc * 32 + 4 * k4];
    }
    __syncthreads();
#pragma unroll
    for (int k4 = 0; k4 < 8; ++k4) {
      float4 a[8];
#pragma unroll
      for (int i = 0; i < 8; ++i)
        a[i] = As4[8 * tb + i][k4 ^ i ^ (tb & 7)];
#pragma unroll
      for (int j = 0; j < 4; ++j) {
        int r = 4 * tn + j;
        float4 bf = Bs4[r][k4 ^ (r & 7) ^ ((r >> 3) & 7)];
#pragma unroll
        for (int i = 0; i < 8; ++i)
          acc[i][j] += a[i].x * bf.x + a[i].y * bf.y
                     + a[i].z * bf.z + a[i].w * bf.w;
      }
    }
  }

  const int s_lc = 2 * bx + (tb >> 3);
  const int brow = 8 * (tb & 7);
#pragma unroll
  for (int j = 0; j < 4; ++j) {
    int n = by * 128 + 4 * tn + j;
    float bs = bias[n];
    int g = n >> 9, u = n & 511;
    size_t base = ((((size_t)d * dstride + buf_base + s_lc) * 3 + g) * HDIM + u) * BATCH + brow;
    float4 v0 = { acc[0][j] + bs, acc[1][j] + bs, acc[2][j] + bs, acc[3][j] + bs };
    float4 v1 = { acc[4][j] + bs, acc[5][j] + bs, acc[6][j] + bs, acc[7][j] + bs };
    *(float4*)&gi[base]     = v0;
    *(float4*)&gi[base + 4] = v1;
  }
}

// ---------------- Phase B: barriered recurrent scan (v8) ----------------
// 256 WGs x 256 thr. WG = (dir, 4 hidden units); 1 unit per wave.
// v8: weights live in VGPRs distributed across lanes (lane L holds
// w[8L..8L+7] per gate, loaded ONCE per dispatch) and are broadcast at
// use via v_readlane (VALU pipe). Eliminates all 384 wave-uniform LDS
// weight reads per wave per step; h-reads (128 b128) remain the only
// LDS dot traffic. FMA expression shape identical -> bitwise-same h.
// h via sc0sc1 global exchange; split-half staging overlap; epoch barrier.
__global__ __launch_bounds__(256, 1) void scan_kernel(
    const float* __restrict__ gi, float* __restrict__ hs,
    const float* __restrict__ Whh_f, const float* __restrict__ bhh_f,
    const float* __restrict__ Whh_b, const float* __restrict__ bhh_b,
    unsigned* cnt, int step0, int nsteps)
{
  const int w   = blockIdx.x;
  const int d   = w >> 7;
  const int ub  = w & 127;
  const int tid = threadIdx.x;
  const int tx  = tid & 63;
  const int ty  = __builtin_amdgcn_readfirstlane(tid >> 6);   // 0..3 wave-uniform
  const int u   = 4 * ub + ty;                                 // this wave's unit

  const float* Whh = d ? Whh_b : Whh_f;
  const float* bhh = d ? bhh_b : bhh_f;

  __shared__ float hl2[2][64][260];   // h(t-1) halves: [half][batch][k-local]
  __shared__ float hb[64][4];

  const float br = bhh[u];
  const float bz = bhh[512 + u];
  const float bn = bhh[1024 + u];
  const int us = __builtin_amdgcn_readfirstlane(u);
  const float* wRp = Whh + (size_t)(us        ) * HDIM;
  const float* wZp = Whh + (size_t)(512  + us ) * HDIM;
  const float* wNp = Whh + (size_t)(1024 + us ) * HDIM;
  const int uhalf = u >> 8, ulo = u & 255;

  // ---- one-time distributed weight preload: lane L holds w[8L..8L+7] ----
  f32x4 wrA = *(const f32x4*)&wRp[8 * tx];
  f32x4 wrB = *(const f32x4*)&wRp[8 * tx + 4];
  f32x4 wzA = *(const f32x4*)&wZp[8 * tx];
  f32x4 wzB = *(const f32x4*)&wZp[8 * tx + 4];
  f32x4 wnA = *(const f32x4*)&wNp[8 * tx];
  f32x4 wnB = *(const f32x4*)&wNp[8 * tx + 4];

  // prefetch gi for step 0
  float ir, iz, in_;
  {
    const float* gb = gi + ((size_t)d * nsteps) * 3 * HDIM * BATCH;
    ir  = gb[((size_t)0 * HDIM + u) * BATCH + tx];
    iz  = gb[((size_t)1 * HDIM + u) * BATCH + tx];
    in_ = gb[((size_t)2 * HDIM + u) * BATCH + tx];
  }

  for (int l = 0; l < nsteps; ++l) {
    const int gs      = step0 + l;
    const int t_store = (d == 0) ? gs : (S_LEN - 1 - gs);
    const int t_prev  = (d == 0) ? (gs - 1) : (S_LEN - gs);

    float aR = 0.f, aZ = 0.f, aN = 0.f, hp = 0.f;

    if (gs > 0) {
      const float* hpg = hs + ((size_t)d * S_LEN + t_prev) * HDIM * BATCH;
      f32x4 buf[32];
      // issue all 32 loads: j<16 -> k half 0, j>=16 -> k half 1
#pragma unroll
      for (int j = 0; j < 32; ++j) {
        int half = j >> 4;
        int flat = tid + 256 * (j & 15);          // 0..4095 float4s per half
        ld_b128_sc(&buf[j], &hpg[(size_t)(flat >> 6) * HDIM + half * 256 + 4 * (flat & 63)]);
      }
      asm volatile("s_waitcnt vmcnt(16)" ::: "memory");   // half 0 arrived
      __builtin_amdgcn_sched_barrier(0);
#pragma unroll
      for (int j = 0; j < 16; ++j) {
        int flat = tid + 256 * j;
        *(f32x4*)&hl2[0][flat >> 6][4 * (flat & 63)] = buf[j];
      }
      __syncthreads();

      if (uhalf == 0) hp = hl2[0][tx][ulo];
      {
        const float* hrow = &hl2[0][tx][0];
#pragma unroll 4
        for (int cc = 0; cc < 32; ++cc) {         // k = 8cc .. 8cc+7 (lane cc)
          float r0 = rdl(wrA[0], cc), r1 = rdl(wrA[1], cc),
                r2 = rdl(wrA[2], cc), r3 = rdl(wrA[3], cc);
          float z0 = rdl(wzA[0], cc), z1 = rdl(wzA[1], cc),
                z2 = rdl(wzA[2], cc), z3 = rdl(wzA[3], cc);
          float n0 = rdl(wnA[0], cc), n1 = rdl(wnA[1], cc),
                n2 = rdl(wnA[2], cc), n3 = rdl(wnA[3], cc);
          f32x4 h4 = *(const f32x4*)&hrow[8 * cc];
          aR += h4.x * r0 + h4.y * r1 + h4.z * r2 + h4.w * r3;
          aZ += h4.x * z0 + h4.y * z1 + h4.z * z2 + h4.w * z3;
          aN += h4.x * n0 + h4.y * n1 + h4.z * n2 + h4.w * n3;
          r0 = rdl(wrB[0], cc); r1 = rdl(wrB[1], cc);
          r2 = rdl(wrB[2], cc); r3 = rdl(wrB[3], cc);
          z0 = rdl(wzB[0], cc); z1 = rdl(wzB[1], cc);
          z2 = rdl(wzB[2], cc); z3 = rdl(wzB[3], cc);
          n0 = rdl(wnB[0], cc); n1 = rdl(wnB[1], cc);
          n2 = rdl(wnB[2], cc); n3 = rdl(wnB[3], cc);
          f32x4 h4b = *(const f32x4*)&hrow[8 * cc + 4];
          aR += h4b.x * r0 + h4b.y * r1 + h4b.z * r2 + h4b.w * r3;
          aZ += h4b.x * z0 + h4b.y * z1 + h4b.z * z2 + h4b.w * z3;
          aN += h4b.x * n0 + h4b.y * n1 + h4b.z * n2 + h4b.w * n3;
        }
      }

      asm volatile("s_waitcnt vmcnt(0)" ::: "memory");    // half 1 arrived
      __builtin_amdgcn_sched_barrier(0);
#pragma unroll
      for (int j = 16; j < 32; ++j) {
        int flat = tid + 256 * (j & 15);
        *(f32x4*)&hl2[1][flat >> 6][4 * (flat & 63)] = buf[j];
      }
      __syncthreads();

      if (uhalf == 1) hp = hl2[1][tx][ulo];
      {
        const float* hrow = &hl2[1][tx][0];
#pragma unroll 4
        for (int cc = 0; cc < 32; ++cc) {         // k = 256+8cc (lane 32+cc)
          const int ln = 32 + cc;
          float r0 = rdl(wrA[0], ln), r1 = rdl(wrA[1], ln),
                r2 = rdl(wrA[2], ln), r3 = rdl(wrA[3], ln);
          float z0 = rdl(wzA[0], ln), z1 = rdl(wzA[1], ln),
                z2 = rdl(wzA[2], ln), z3 = rdl(wzA[3], ln);
          float n0 = rdl(wnA[0], ln), n1 = rdl(wnA[1], ln),
                n2 = rdl(wnA[2], ln), n3 = rdl(wnA[3], ln);
          f32x4 h4 = *(const f32x4*)&hrow[8 * cc];
          aR += h4.x * r0 + h4.y * r1 + h4.z * r2 + h4.w * r3;
          aZ += h4.x * z0 + h4.y * z1 + h4.z * z2 + h4.w * z3;
          aN += h4.x * n0 + h4.y * n1 + h4.z * n2 + h4.w * n3;
          r0 = rdl(wrB[0], ln); r1 = rdl(wrB[1], ln);
          r2 = rdl(wrB[2], ln); r3 = rdl(wrB[3], ln);
          z0 = rdl(wzB[0], ln); z1 = rdl(wzB[1], ln);
          z2 = rdl(wzB[2], ln); z3 = rdl(wzB[3], ln);
          n0 = rdl(wnB[0], ln); n1 = rdl(wnB[1], ln);
          n2 = rdl(wnB[2], ln); n3 = rdl(wnB[3], ln);
          f32x4 h4b = *(const f32x4*)&hrow[8 * cc + 4];
          aR += h4b.x * r0 + h4b.y * r1 + h4b.z * r2 + h4b.w * r3;
          aZ += h4b.x * z0 + h4b.y * z1 + h4b.z * z2 + h4b.w * z3;
          aN += h4b.x * n0 + h4b.y * n1 + h4b.z * n2 + h4b.w * n3;
        }
      }
    }

    float r  = 1.f / (1.f + expf(-(ir + aR + br)));
    float zg = 1.f / (1.f + expf(-(iz + aZ + bz)));
    float n  = tanhf(in_ + r * (aN + bn));
    float hn = (1.f - zg) * n + zg * hp;

    __syncthreads();
    hb[tx][ty] = hn;
    __syncthreads();
    if (tid < 64) {
      f32x4 v = *(const f32x4*)&hb[tid][0];
      st_b128_sc(&hs[(((size_t)d * S_LEN + t_store) * BATCH + tid) * HDIM + 4 * ub], v);
      asm volatile("s_waitcnt vmcnt(0)" ::: "memory");    // wave0: all 64 stores at L3
    }
    // arrive (tid0 is in wave 0 -> ordered after the vmcnt above)
    if (tid == 0)
      __hip_atomic_fetch_add(&cnt[(w & 31) << 4], 1u,
                             __ATOMIC_RELAXED, __HIP_MEMORY_SCOPE_AGENT);
    // prefetch gi(l+1) while waiting
    if (l + 1 < nsteps) {
      const float* gb = gi + ((size_t)d * nsteps + l + 1) * 3 * HDIM * BATCH;
      ir  = gb[((size_t)0 * HDIM + u) * BATCH + tx];
      iz  = gb[((size_t)1 * HDIM + u) * BATCH + tx];
      in_ = gb[((size_t)2 * HDIM + u) * BATCH + tx];
    }
    if (w == 0) {
      if (tid < 32) {                    // all in wave 0: polls precede publish
        unsigned tgt = 8u * (unsigned)(gs + 1);
        while (__hip_atomic_load(&cnt[tid << 4],
                                 __ATOMIC_RELAXED, __HIP_MEMORY_SCOPE_AGENT) < tgt)
          __builtin_amdgcn_s_sleep(1);
      }
      if (tid == 0)
        __hip_atomic_store(&cnt[32 << 4], (unsigned)(gs + 1),
                           __ATOMIC_RELAXED, __HIP_MEMORY_SCOPE_AGENT);
    } else {
      if (tid == 0) {
        while (__hip_atomic_load(&cnt[32 << 4],
                                 __ATOMIC_RELAXED, __HIP_MEMORY_SCOPE_AGENT)
               < (unsigned)(gs + 1))
          __builtin_amdgcn_s_sleep(1);
      }
    }
    __syncthreads();
  }
}

// ---------------- Phase C: pz / z ----------------
__global__ __launch_bounds__(256) void pz_kernel(
    const float* __restrict__ hs, const float* __restrict__ zW,
    const float* __restrict__ zb_, const float* __restrict__ noise,
    float* __restrict__ out)
{
  const int gtid = blockIdx.x * 256 + threadIdx.x;
  const int wave = gtid >> 6;
  const int lane = threadIdx.x & 63;
  const float zb = zb_[0];
  float4 w1 = *(const float4*)&zW[lane * 8];
  float4 w2 = *(const float4*)&zW[lane * 8 + 4];
  float4 w3 = *(const float4*)&zW[512 + lane * 8];
  float4 w4 = *(const float4*)&zW[512 + lane * 8 + 4];
  for (int r = wave; r < S_LEN * BATCH; r += 1024) {
    const float* hf  = hs + (size_t)r * HDIM;
    const float* hbk = hs + (size_t)(S_LEN * BATCH + r) * HDIM;
    float4 a1 = *(const float4*)&hf[lane * 8];
    float4 a2 = *(const float4*)&hf[lane * 8 + 4];
    float4 b1 = *(const float4*)&hbk[lane * 8];
    float4 b2 = *(const float4*)&hbk[lane * 8 + 4];
    float acc = a1.x * w1.x + a1.y * w1.y + a1.z * w1.z + a1.w * w1.w
              + a2.x * w2.x + a2.y * w2.y + a2.z * w2.z + a2.w * w2.w
              + b1.x * w3.x + b1.y * w3.y + b1.z * w3.z + b1.w * w3.w
              + b2.x * w4.x + b2.y * w4.y + b2.z * w4.z + b2.w * w4.w;
#pragma unroll
    for (int off = 32; off > 0; off >>= 1) acc += __shfl_down(acc, off, 64);
    if (lane == 0) {
      float p = 1.f / (1.f + expf(-(acc + zb)));
      out[r] = p;
      out[S_LEN * BATCH + r] = (noise[r] < p) ? 1.f : 0.f;
    }
  }
}

// ---------------- Phase D: per-column stable compaction ----------------
__global__ __launch_bounds__(256) void rat_kernel(
    const int* __restrict__ sent, float* __restrict__ out)
{
  const int b = blockIdx.x;
  const int s = threadIdx.x;
  __shared__ int ps[256];
  const int z = (out[S_LEN * BATCH + s * BATCH + b] > 0.5f) ? 1 : 0;
  ps[s] = z;
  __syncthreads();
#pragma unroll
  for (int off = 1; off < 256; off <<= 1) {
    int v = (s >= off) ? ps[s - off] : 0;
    __syncthreads();
    ps[s] += v;
    __syncthreads();
  }
  const int incl  = ps[s];
  const int total = ps[255];
  const int pos   = incl - z;
  if (z) out[2 * S_LEN * BATCH + pos * BATCH + b] = (float)sent[s * BATCH + b];
  if (s >= total) out[2 * S_LEN * BATCH + s * BATCH + b] = 0.f;
  if (s == 0) out[3 * S_LEN * BATCH + b] = (float)total;
}

extern "C" void kernel_launch(void* const* d_in, const int* in_sizes, int n_in,
                              void* d_out, int out_size, void* d_ws, size_t ws_size,
                              hipStream_t stream)
{
  const int*   sent  = (const int*)  d_in[0];
  const float* noise = (const float*)d_in[1];
  const float* emb   = (const float*)d_in[2];
  const float* Wih_f = (const float*)d_in[3];
  const float* Whh_f = (const float*)d_in[4];
  const float* bih_f = (const float*)d_in[5];
  const float* bhh_f = (const float*)d_in[6];
  const float* Wih_b = (const float*)d_in[7];
  const float* Whh_b = (const float*)d_in[8];
  const float* bih_b = (const float*)d_in[9];
  const float* bhh_b = (const float*)d_in[10];
  const float* zW    = (const float*)d_in[11];
  const float* zb    = (const float*)d_in[12];
  float* out = (float*)d_out;

  float* base = (float*)d_ws;
  unsigned* cnt = (unsigned*)base;                         // 4 KB reserved
  float* hs = base + 1024;                                 // 67.1 MB
  float* gi = hs + (size_t)2 * S_LEN * HDIM * BATCH;       // rest

  const size_t HS_BYTES = (size_t)2 * S_LEN * HDIM * BATCH * 4;
  const size_t PER_SLOT = (size_t)2 * 3 * HDIM * BATCH * 4;    // 786432 B
  size_t avail = (ws_size > 4096 + HS_BYTES) ? ws_size - 4096 - HS_BYTES : 0;
  int nslots = 64;
  if (avail >= 256 * PER_SLOT)      nslots = 256;
  else if (avail >= 128 * PER_SLOT) nslots = 128;
  const int nchunk = S_LEN / nslots;

  (void)hipMemsetAsync(cnt, 0, 4096, stream);
  for (int c = 0; c < nchunk; ++c) {
    for (int k = 0; k < nslots / 64; ++k)
      gi_gemm<<<dim3(32, 12, 2), 512, 0, stream>>>(
          sent, emb, Wih_f, bih_f, Wih_b, bih_b, gi,
          c * nslots + 64 * k, 64 * k, nslots);
    scan_kernel<<<dim3(256), 256, 0, stream>>>(
        gi, hs, Whh_f, bhh_f, Whh_b, bhh_b, cnt, c * nslots, nslots);
  }
  pz_kernel<<<dim3(256), 256, 0, stream>>>(hs, zW, zb, noise, out);
  rat_kernel<<<dim3(BATCH), 256, 0, stream>>>(sent, out);
}